// Round 1
// baseline (141.873 us; speedup 1.0000x reference)
//
#include <hip/hip_runtime.h>
#include <hip/hip_bf16.h>

#define SEQ 1024
#define EMBD 128

typedef __attribute__((ext_vector_type(8))) short s16x8;
typedef __attribute__((ext_vector_type(4))) float f32x4;
typedef __attribute__((ext_vector_type(4))) unsigned int u32x4;

// bf16 weight offsets in workspace (elements)
#define W1_OFF 0
#define W2_OFF (512 * 640)
#define W3_OFF (W2_OFF + 256 * 512)
#define W4_OFF (W3_OFF + 128 * 256)
#define WTOT   (W4_OFF + 38 * 128)

__device__ __forceinline__ unsigned int f2bf(float f) {
    unsigned int u = __float_as_uint(f);
    return (u + 0x7fffu + ((u >> 16) & 1u)) >> 16;   // RNE
}

__global__ void convert_w_kernel(const float* __restrict__ w1, const float* __restrict__ w2,
                                 const float* __restrict__ w3, const float* __restrict__ w4,
                                 unsigned short* __restrict__ dst) {
    int i = blockIdx.x * blockDim.x + threadIdx.x;
    if (i >= WTOT) return;
    float f;
    if (i < W2_OFF)      f = w1[i];
    else if (i < W3_OFF) f = w2[i - W2_OFF];
    else if (i < W4_OFF) f = w3[i - W3_OFF];
    else                 f = w4[i - W4_OFF];
    dst[i] = (unsigned short)f2bf(f);
}

// LDS layout (bytes):
//   region A @ 0      (32768): x tile (68 rows x 256B) -> later h2 (64 x 512B)
//   region B @ 32768  (65536): h1 (64 x 1024B)         -> later h3 (64 x 256B)
#define RB 32768

__launch_bounds__(512, 1)
__global__ void fused_mlp(const int* __restrict__ tok,
                          const float* __restrict__ emb,
                          const unsigned short* __restrict__ wbf,
                          const float* __restrict__ b1,
                          const float* __restrict__ b2,
                          const float* __restrict__ b3,
                          const float* __restrict__ b4,
                          float* __restrict__ out) {
    __shared__ char smem[98304];
    const int tid  = threadIdx.x;
    const int lane = tid & 63;
    const int wave = tid >> 6;
    const int l15  = lane & 15;
    const int l4   = lane >> 4;                // 0..3
    const int r0   = blockIdx.x * 64;          // first output row of this block
    const int s0   = r0 & (SEQ - 1);
    const int bat  = r0 >> 10;

    // ---------- stage embedded x tile: rows s0-2 .. s0+65 (68 rows) x 128 dims, bf16
    for (int chunk = tid; chunk < 68 * 16; chunk += 512) {
        const int row = chunk >> 4;            // 0..67
        const int c   = chunk & 15;            // 16B chunk within row (8 bf16)
        const int sp  = s0 - 2 + row;
        u32x4 v = {0u, 0u, 0u, 0u};
        if (sp >= 0 && sp < SEQ) {
            const int t = tok[bat * SEQ + sp];
            const float* e = emb + t * EMBD + c * 8;
            unsigned int p0 = f2bf(e[0]) | (f2bf(e[1]) << 16);
            unsigned int p1 = f2bf(e[2]) | (f2bf(e[3]) << 16);
            unsigned int p2 = f2bf(e[4]) | (f2bf(e[5]) << 16);
            unsigned int p3 = f2bf(e[6]) | (f2bf(e[7]) << 16);
            v = (u32x4){p0, p1, p2, p3};
        }
        int byte = row * 256 + c * 16;
        byte ^= (row & 7) << 4;
        *reinterpret_cast<u32x4*>(smem + byte) = v;
    }
    __syncthreads();

    // ---------- GEMM1: [64,640] x W1^T[640,512] -> h1 bf16 in LDS (region B)
    {
        f32x4 acc[4][4];
        #pragma unroll
        for (int m = 0; m < 4; ++m)
            #pragma unroll
            for (int n = 0; n < 4; ++n) acc[m][n] = (f32x4){0.f, 0.f, 0.f, 0.f};
        const int nb = wave * 64;              // this wave's N base (512 / 8 waves)
        for (int ks = 0; ks < 20; ++ks) {
            const int j    = ks >> 2;          // context offset 0..4
            const int doff = (ks & 3) * 32;    // dim offset within embedding
            const int kg   = ks * 32 + 8 * l4; // global k of this lane's 8 elems
            s16x8 a[4];
            #pragma unroll
            for (int m = 0; m < 4; ++m) {
                const int row = m * 16 + l15 + j;      // x row (shifted by context)
                int byte = row * 256 + (doff + 8 * l4) * 2;
                byte ^= (row & 7) << 4;
                a[m] = *reinterpret_cast<const s16x8*>(smem + byte);
            }
            #pragma unroll
            for (int n = 0; n < 4; ++n) {
                const int col = nb + n * 16 + l15;
                s16x8 b = *reinterpret_cast<const s16x8*>(wbf + W1_OFF + col * 640 + kg);
                #pragma unroll
                for (int m = 0; m < 4; ++m)
                    acc[m][n] = __builtin_amdgcn_mfma_f32_16x16x32_bf16(a[m], b, acc[m][n], 0, 0, 0);
            }
        }
        #pragma unroll
        for (int n = 0; n < 4; ++n) {
            const int col  = nb + n * 16 + l15;
            const float bi = b1[col];
            #pragma unroll
            for (int m = 0; m < 4; ++m)
                #pragma unroll
                for (int q = 0; q < 4; ++q) {
                    const int row = m * 16 + l4 * 4 + q;
                    float v = fmaxf(acc[m][n][q] + bi, 0.f);
                    int byte = RB + row * 1024 + col * 2;
                    byte ^= (row & 7) << 4;
                    *reinterpret_cast<unsigned short*>(smem + byte) = (unsigned short)f2bf(v);
                }
        }
    }
    __syncthreads();

    // ---------- GEMM2: [64,512] x W2^T[512,256] -> h2 bf16 in LDS (region A)
    {
        f32x4 acc[4][2];
        #pragma unroll
        for (int m = 0; m < 4; ++m)
            #pragma unroll
            for (int n = 0; n < 2; ++n) acc[m][n] = (f32x4){0.f, 0.f, 0.f, 0.f};
        const int nb = wave * 32;              // 256 / 8 waves
        for (int ks = 0; ks < 16; ++ks) {
            const int kg = ks * 32 + 8 * l4;
            s16x8 a[4];
            #pragma unroll
            for (int m = 0; m < 4; ++m) {
                const int row = m * 16 + l15;
                int byte = RB + row * 1024 + kg * 2;
                byte ^= (row & 7) << 4;
                a[m] = *reinterpret_cast<const s16x8*>(smem + byte);
            }
            #pragma unroll
            for (int n = 0; n < 2; ++n) {
                const int col = nb + n * 16 + l15;
                s16x8 b = *reinterpret_cast<const s16x8*>(wbf + W2_OFF + col * 512 + kg);
                #pragma unroll
                for (int m = 0; m < 4; ++m)
                    acc[m][n] = __builtin_amdgcn_mfma_f32_16x16x32_bf16(a[m], b, acc[m][n], 0, 0, 0);
            }
        }
        #pragma unroll
        for (int n = 0; n < 2; ++n) {
            const int col  = nb + n * 16 + l15;
            const float bi = b2[col];
            #pragma unroll
            for (int m = 0; m < 4; ++m)
                #pragma unroll
                for (int q = 0; q < 4; ++q) {
                    const int row = m * 16 + l4 * 4 + q;
                    float v = fmaxf(acc[m][n][q] + bi, 0.f);
                    int byte = row * 512 + col * 2;
                    byte ^= (row & 7) << 4;
                    *reinterpret_cast<unsigned short*>(smem + byte) = (unsigned short)f2bf(v);
                }
        }
    }
    __syncthreads();

    // ---------- GEMM3: [64,256] x W3^T[256,128] -> h3 bf16 in LDS (region B)
    {
        f32x4 acc[4];
        #pragma unroll
        for (int m = 0; m < 4; ++m) acc[m] = (f32x4){0.f, 0.f, 0.f, 0.f};
        const int nb = wave * 16;              // 128 / 8 waves
        for (int ks = 0; ks < 8; ++ks) {
            const int kg = ks * 32 + 8 * l4;
            const int col = nb + l15;
            s16x8 b = *reinterpret_cast<const s16x8*>(wbf + W3_OFF + col * 256 + kg);
            #pragma unroll
            for (int m = 0; m < 4; ++m) {
                const int row = m * 16 + l15;
                int byte = row * 512 + kg * 2;
                byte ^= (row & 7) << 4;
                s16x8 a = *reinterpret_cast<const s16x8*>(smem + byte);
                acc[m] = __builtin_amdgcn_mfma_f32_16x16x32_bf16(a, b, acc[m], 0, 0, 0);
            }
        }
        const int col  = nb + l15;
        const float bi = b3[col];
        #pragma unroll
        for (int m = 0; m < 4; ++m)
            #pragma unroll
            for (int q = 0; q < 4; ++q) {
                const int row = m * 16 + l4 * 4 + q;
                float v = fmaxf(acc[m][q] + bi, 0.f);
                int byte = RB + row * 256 + col * 2;
                byte ^= (row & 7) << 4;
                *reinterpret_cast<unsigned short*>(smem + byte) = (unsigned short)f2bf(v);
            }
    }
    __syncthreads();

    // ---------- GEMM4: [64,128] x W4^T[128,38] -> out fp32 (waves 0..3, one M-tile each)
    if (wave < 4) {
        f32x4 acc[3];
        #pragma unroll
        for (int n = 0; n < 3; ++n) acc[n] = (f32x4){0.f, 0.f, 0.f, 0.f};
        const int m = wave;
        for (int ks = 0; ks < 4; ++ks) {
            const int kg  = ks * 32 + 8 * l4;
            const int row = m * 16 + l15;
            int byte = RB + row * 256 + kg * 2;
            byte ^= (row & 7) << 4;
            s16x8 a = *reinterpret_cast<const s16x8*>(smem + byte);
            #pragma unroll
            for (int n = 0; n < 3; ++n) {
                const int col = n * 16 + l15;
                s16x8 b = {0, 0, 0, 0, 0, 0, 0, 0};
                if (col < 38)
                    b = *reinterpret_cast<const s16x8*>(wbf + W4_OFF + col * 128 + kg);
                acc[n] = __builtin_amdgcn_mfma_f32_16x16x32_bf16(a, b, acc[n], 0, 0, 0);
            }
        }
        #pragma unroll
        for (int n = 0; n < 3; ++n) {
            const int col = n * 16 + l15;
            if (col < 38) {
                const float bi = b4[col];
                #pragma unroll
                for (int q = 0; q < 4; ++q) {
                    const int rg = r0 + m * 16 + l4 * 4 + q;
                    out[rg * 38 + col] = acc[n][q] + bi;
                }
            }
        }
    }
}

extern "C" void kernel_launch(void* const* d_in, const int* in_sizes, int n_in,
                              void* d_out, int out_size, void* d_ws, size_t ws_size,
                              hipStream_t stream) {
    const int*   tok = (const int*)d_in[0];
    const float* emb = (const float*)d_in[1];
    const float* W1  = (const float*)d_in[2];
    const float* b1  = (const float*)d_in[3];
    const float* W2  = (const float*)d_in[4];
    const float* b2  = (const float*)d_in[5];
    const float* W3  = (const float*)d_in[6];
    const float* b3  = (const float*)d_in[7];
    const float* W4  = (const float*)d_in[8];
    const float* b4  = (const float*)d_in[9];
    float* out = (float*)d_out;
    unsigned short* wbf = (unsigned short*)d_ws;

    convert_w_kernel<<<(WTOT + 255) / 256, 256, 0, stream>>>(W1, W2, W3, W4, wbf);
    fused_mlp<<<1024, 512, 0, stream>>>(tok, emb, wbf, b1, b2, b3, b4, out);
}